// Round 10
// baseline (141.622 us; speedup 1.0000x reference)
//
#include <hip/hip_runtime.h>
#include <hip/hip_bf16.h>

// Problem constants
#define BATCH 64
#define NATOM 120
#define NNB 10
#define NBOND 250
#define AFDIM 82
#define BFDIM 6
#define HREAL 300
#define HP 320            // padded H (bf16 activation row stride); pad cols hold exact 0
#define NCT32 10          // 10 col-tiles of 32 -> 320
#define MA (BATCH*NATOM)  // 7680
#define MB (BATCH*NBOND)  // 16000

typedef short short8 __attribute__((ext_vector_type(8)));   // 8 bf16 (4 VGPRs)
typedef float f32x16 __attribute__((ext_vector_type(16)));  // 32x32 MFMA accumulator
typedef unsigned int u32;
typedef u32 u32x2 __attribute__((ext_vector_type(2)));
typedef unsigned short u16;
typedef unsigned char u8;

__device__ __forceinline__ float bflo(u32 v) { return __builtin_bit_cast(float, v << 16); }
__device__ __forceinline__ float bfhi(u32 v) { return __builtin_bit_cast(float, v & 0xffff0000u); }
__device__ __forceinline__ float bfu(u16 v) { return __builtin_bit_cast(float, (u32)v << 16); }
__device__ __forceinline__ u16 f2bf(float f) {
    __hip_bfloat16 h = __float2bfloat16(f);
    return __builtin_bit_cast(u16, h);
}
__device__ __forceinline__ int imin(int a, int b) { return a < b ? a : b; }

// ================= prep: weight packs + packed nbr table (convs & bond GEMM eliminated) =================
struct PackJob { const float* W; short8* dst; int Kreal, KT, KTfull, ktOff, blk0; };
struct Prep {
    const int *mn, *agp, *bgp; u32* pk;          // packed nbr table [MA*NNB]
    PackJob j[6];
};

#define PACK_BLKS 265     // 15 + 50*5
#define PK_BASE   PACK_BLKS
#define PK_BLKS   300     // MA*NNB/256 = 76800/256
#define PREP_BLKS (PK_BASE + PK_BLKS)   // 565

__global__ __launch_bounds__(256) void prep_all(Prep cfg) {
    const int bid = blockIdx.x;
    const int tid = threadIdx.x;
    if (bid < PK_BASE) {
        int ji = 0;
#pragma unroll
        for (int i = 1; i < 6; ++i) if (bid >= cfg.j[i].blk0) ji = i;
        const PackJob J = cfg.j[ji];
        int id = (bid - J.blk0) * 256 + tid;
        int n = NCT32 * J.KT * 64;
        if (id >= n) return;
        int lane = id & 63;
        int kt = (id >> 6) % J.KT;
        int ct = id / (J.KT * 64);
        int col = ct * 32 + (lane & 31);
        int kbase = kt * 16 + (lane >> 5) * 8;
        short8 v;
#pragma unroll
        for (int jj = 0; jj < 8; ++jj) {
            int k = kbase + jj;
            float f = (k < J.Kreal && col < HREAL) ? J.W[(size_t)k * HREAL + col] : 0.f;
            v[jj] = (short)f2bf(f);
        }
        J.dst[(size_t)(ct * J.KTfull + J.ktOff + kt) * 64 + lane] = v;
    } else {
        int id = (bid - PK_BASE) * 256 + tid;     // exact multiple (76800)
        u32 w = 0;
        if (cfg.mn[id]) w = 0x80000000u | ((u32)cfg.agp[id] << 16) | (u32)cfg.bgp[id];
        cfg.pk[id] = w;
    }
}

// ================= fc1: af0 = relu(A1 @ W_fc1), fp32 A read inline (conv folded in) =================
// 2-wave blocks, 64 rows x 2 ct; grid (120,5). Values identical to conv-then-GEMM path
// (same f2bf conversion point, same MFMA).
__global__ __launch_bounds__(128)
void k_fc1(const float* __restrict__ A1,          // [MA][82] fp32
           const short8* __restrict__ pW1,
           __hip_bfloat16* __restrict__ af0) {
    __shared__ short8 Wl[2 * 6 * 64];
    const int tid  = threadIdx.x;
    const int lane = tid & 63;
    const int wv   = tid >> 6;
    const int m0   = blockIdx.x * 64 + wv * 32;
    const int ct0  = blockIdx.y * 2;
    const int r1   = m0 + (lane & 31);
    const int koff = (lane >> 5) * 8;

    {
        const short8* wsrc = pW1 + (size_t)ct0 * 6 * 64;
#pragma unroll
        for (int i = 0; i < 6; ++i) Wl[i * 128 + tid] = wsrc[i * 128 + tid];
    }
    __syncthreads();

    const float* src = A1 + (size_t)r1 * AFDIM;
    short8 a[6];
#pragma unroll
    for (int g = 0; g < 6; ++g) {
#pragma unroll
        for (int j = 0; j < 8; ++j) {
            const int k = g * 16 + koff + j;
            const float f = (k < AFDIM) ? src[k] : 0.f;
            a[g][j] = (short)f2bf(f);
        }
    }

    f32x16 acc[2];
#pragma unroll
    for (int r = 0; r < 16; ++r) { acc[0][r] = 0.f; acc[1][r] = 0.f; }
    const short8* w0 = Wl + lane;
    const short8* w1 = Wl + 6 * 64 + lane;
#pragma unroll
    for (int g = 0; g < 6; ++g) {
        acc[0] = __builtin_amdgcn_mfma_f32_32x32x16_bf16(a[g], w0[g * 64], acc[0], 0, 0, 0);
        acc[1] = __builtin_amdgcn_mfma_f32_32x32x16_bf16(a[g], w1[g * 64], acc[1], 0, 0, 0);
    }
#pragma unroll
    for (int c = 0; c < 2; ++c) {
        const int col = (ct0 + c) * 32 + (lane & 31);
#pragma unroll
        for (int r = 0; r < 16; ++r) {
            const int row = m0 + (r & 3) + 8 * (r >> 2) + 4 * (lane >> 5);
            af0[(size_t)row * HP + col] = __float2bfloat16(fmaxf(acc[c][r], 0.f));
        }
    }
}

// ================= bot GEMM (R7-proven): afn = relu([af|nei]@W_ga + b_ga), 2 ct, 80KB panel =================
#define BOT_LDS (2 * 40 * 64 * 16)     // 81920 B -> 2 blocks/CU
__global__ __launch_bounds__(256)
void k_gemm_bot(const __hip_bfloat16* __restrict__ af,
                const __hip_bfloat16* __restrict__ neib,
                const short8* __restrict__ W,
                const float* __restrict__ b_ga,
                __hip_bfloat16* __restrict__ afn) {
    extern __shared__ short8 Wl[];             // [2*40*64]
    const int tid  = threadIdx.x;
    const int lane = tid & 63;
    const int wv   = tid >> 6;
    const int m0   = blockIdx.x * 128 + wv * 32;
    const int ct0  = blockIdx.y * 2;
    const int r1   = m0 + (lane & 31);
    const int koff = (lane >> 5) * 8;

    {
        const short8* wsrc = W + (size_t)ct0 * 40 * 64;
#pragma unroll
        for (int i = 0; i < 20; ++i) Wl[i * 256 + tid] = wsrc[i * 256 + tid];
    }
    __syncthreads();

    f32x16 acc[2];
#pragma unroll
    for (int r = 0; r < 16; ++r) { acc[0][r] = 0.f; acc[1][r] = 0.f; }
    const short8* w0 = Wl + lane;
    const short8* w1 = Wl + 40 * 64 + lane;

#pragma unroll
    for (int ch = 0; ch < 4; ++ch) {
        short8 a[10];
#pragma unroll
        for (int kt = 0; kt < 10; ++kt) {
            const int g = ch * 10 + kt;
            if (g < 20)
                a[kt] = *reinterpret_cast<const short8*>(af + (size_t)r1 * HP + g * 16 + koff);
            else
                a[kt] = *reinterpret_cast<const short8*>(neib + (size_t)r1 * HP + (g - 20) * 16 + koff);
        }
#pragma unroll
        for (int kt = 0; kt < 10; ++kt) {
            const int g = ch * 10 + kt;
            acc[0] = __builtin_amdgcn_mfma_f32_32x32x16_bf16(a[kt], w0[g * 64], acc[0], 0, 0, 0);
            acc[1] = __builtin_amdgcn_mfma_f32_32x32x16_bf16(a[kt], w1[g * 64], acc[1], 0, 0, 0);
        }
    }

#pragma unroll
    for (int c = 0; c < 2; ++c) {
        const int col = (ct0 + c) * 32 + (lane & 31);
        const float bb = (col < HREAL) ? b_ga[col] : 0.f;
#pragma unroll
        for (int r = 0; r < 16; ++r) {
            const int row = m0 + (r & 3) + 8 * (r >> 2) + 4 * (lane >> 5);
            afn[(size_t)row * HP + col] = __float2bfloat16(fmaxf(acc[c][r] + bb, 0.f));
        }
    }
}

// ================= fused nu-GEMM + gather; bondgc slice computed on the fly (rank-6) =================
// LDS: WL 20480 | TL 7680 | BL 16000 | PL 4800 | BFL 4000 | WS 384 = 53344 -> 3 blocks/CU
#define NUG_LDS (20480 + 7680 + 16000 + 4800 + 4000 + 384)
__global__ __launch_bounds__(256)
void k_nu_gather(const __hip_bfloat16* __restrict__ af,
                 const short8* __restrict__ pWnei,
                 const float* __restrict__ bond,      // [B][250][6] fp32
                 const float* __restrict__ Wgn_bond,  // W_gc_nei + 300*300, [6][300]
                 const float* __restrict__ b_gn,      // [300]
                 const u32* __restrict__ pk,
                 u32* __restrict__ nei) {             // [MA][160]
    extern __shared__ char smraw[];
    short8* WL  = (short8*)smraw;                  // [20*64]
    u16*    TL  = (u16*)(smraw + 20480);           // [120][32]
    u16*    BLh = (u16*)(smraw + 28160);           // [250][32] bondgc slice
    u32*    PL  = (u32*)(smraw + 44160);           // [1200]
    u16*    BFL = (u16*)(smraw + 48960);           // [250][8] bond bf16
    u16*    WS  = (u16*)(smraw + 52960);           // [6][32]  W bond-part slice bf16
    u32*    BL  = (u32*)BLh;
    const int b   = blockIdx.x;
    const int ct  = blockIdx.y;
    const int tid = threadIdx.x;

    // ---- stage ----
    {
        const short8* wsrc = pWnei + (size_t)ct * 20 * 64;
#pragma unroll
        for (int i = 0; i < 5; ++i) WL[i * 256 + tid] = wsrc[i * 256 + tid];
    }
    for (int i = tid; i < NBOND * 8; i += 256) {
        const int r = i >> 3, k = i & 7;
        const float f = (k < BFDIM) ? bond[(size_t)(b * NBOND + r) * BFDIM + k] : 0.f;
        BFL[i] = f2bf(f);
    }
    if (tid < 192) {
        const int k = tid >> 5, c = tid & 31;
        const int col = ct * 32 + c;
        const float f = (col < HREAL) ? Wgn_bond[(size_t)k * HREAL + col] : 0.f;
        WS[tid] = f2bf(f);
    }
    for (int i = tid; i < NATOM * NNB; i += 256) PL[i] = pk[b * NATOM * NNB + i];
    __syncthreads();

    // ---- bondgc slice: BL[r][col] = bf16( sum_k bond[r,k]*W[k,col] + bias[col] ) ----
    for (int i = tid; i < NBOND * 16; i += 256) {
        const int r = i >> 4, cp = i & 15;
        const int col0 = ct * 32 + 2 * cp;
        float lo = 0.f, hi = 0.f;
#pragma unroll
        for (int k = 0; k < BFDIM; ++k) {
            const float bv = bfu(BFL[r * 8 + k]);
            const u32 wv2 = *reinterpret_cast<const u32*>(&WS[k * 32 + 2 * cp]);
            lo += bv * bflo(wv2);
            hi += bv * bfhi(wv2);
        }
        const float v0 = (col0     < HREAL) ? lo + b_gn[col0]     : 0.f;
        const float v1 = (col0 + 1 < HREAL) ? hi + b_gn[col0 + 1] : 0.f;
        BL[r * 16 + cp] = (u32)f2bf(v0) | ((u32)f2bf(v1) << 16);
    }

    // ---- GEMM: TL = af[b] @ W_nei[ct] ----
    {
        const int lane = tid & 63;
        const int wv   = tid >> 6;
        const int r1   = imin(wv * 32 + (lane & 31), NATOM - 1);
        const int koff = (lane >> 5) * 8;
        const __hip_bfloat16* arow = af + (size_t)(b * NATOM + r1) * HP + koff;
        f32x16 acc;
#pragma unroll
        for (int r = 0; r < 16; ++r) acc[r] = 0.f;
        const short8* w0 = WL + lane;
#pragma unroll
        for (int ch = 0; ch < 2; ++ch) {
            short8 a[10];
#pragma unroll
            for (int kt = 0; kt < 10; ++kt)
                a[kt] = *reinterpret_cast<const short8*>(arow + (ch * 10 + kt) * 16);
#pragma unroll
            for (int kt = 0; kt < 10; ++kt)
                acc = __builtin_amdgcn_mfma_f32_32x32x16_bf16(a[kt], w0[(ch * 10 + kt) * 64], acc, 0, 0, 0);
        }
        const int col = lane & 31;
#pragma unroll
        for (int r = 0; r < 16; ++r) {
            const int row = wv * 32 + (r & 3) + 8 * (r >> 2) + 4 * (lane >> 5);
            if (row < NATOM) TL[row * 32 + col] = f2bf(acc[r]);
        }
    }
    __syncthreads();

    // ---- gather: nei = sum_j relu(T[ag] + bondgc[bg]) ----
    for (int i = tid; i < NATOM * 16; i += 256) {
        const int row = i >> 4, cp = i & 15;
        float lo = 0.f, hi = 0.f;
#pragma unroll
        for (int j = 0; j < NNB; ++j) {
            const u32 w = PL[row * NNB + j];
            if ((int)w < 0) {
                const int a  = (w >> 16) & 0xff;
                const int bo = w & 0xffff;
                const u32 ta = *reinterpret_cast<const u32*>(&TL[a * 32 + 2 * cp]);
                const u32 tb = BL[bo * 16 + cp];
                lo += fmaxf(bflo(ta) + bflo(tb), 0.f);
                hi += fmaxf(bfhi(ta) + bfhi(tb), 0.f);
            }
        }
        nei[(size_t)(b * NATOM + row) * (HP / 2) + ct * 16 + cp] =
            (u32)f2bf(lo) | ((u32)f2bf(hi) << 16);
    }
}

// ================= fused final GEMM + product; bnb slice computed on the fly =================
// LDS: WL 40960 | SL 7680 | AL 7680 | BL 16000 | PL 4800 | ML 120 | BFL 4000 | WS 384 = 81624 -> 2/CU
#define FIN_LDS (40960 + 7680 + 7680 + 16000 + 4800 + 120 + 4000 + 384)
__global__ __launch_bounds__(256)
void k_final_fused(const __hip_bfloat16* __restrict__ af,
                   const short8* __restrict__ pWfd,    // fc2 ct 0..9 | fc2a ct 10..19
                   const float* __restrict__ bond,     // [B][250][6] fp32
                   const float* __restrict__ W_fc2b,   // [6][300] fp32
                   const u32* __restrict__ pk,
                   const int* __restrict__ maska,
                   float* __restrict__ out) {          // [MA][300]
    extern __shared__ char smraw[];
    short8* WL  = (short8*)smraw;                      // [2*20*64]
    u16*    SL  = (u16*)(smraw + 40960);               // selfF [120][32]
    u16*    AL  = (u16*)(smraw + 48640);               // A2f   [120][32]
    u16*    BLh = (u16*)(smraw + 56320);               // bnb   [250][32]
    u32*    PL  = (u32*)(smraw + 72320);               // [1200]
    u8*     ML  = (u8*)(smraw + 77120);                // [120]
    u16*    BFL = (u16*)(smraw + 77240);               // [250][8]
    u16*    WS  = (u16*)(smraw + 81240);               // [6][32]
    u32*    BL  = (u32*)BLh;
    const int b   = blockIdx.x;
    const int ct  = blockIdx.y;
    const int tid = threadIdx.x;

    // ---- stage ----
    {
        const short8* w2  = pWfd + (size_t)ct * 20 * 64;
        const short8* w2a = pWfd + (size_t)(NCT32 + ct) * 20 * 64;
#pragma unroll
        for (int i = 0; i < 5; ++i) {
            WL[i * 256 + tid]        = w2[i * 256 + tid];
            WL[1280 + i * 256 + tid] = w2a[i * 256 + tid];
        }
    }
    for (int i = tid; i < NBOND * 8; i += 256) {
        const int r = i >> 3, k = i & 7;
        const float f = (k < BFDIM) ? bond[(size_t)(b * NBOND + r) * BFDIM + k] : 0.f;
        BFL[i] = f2bf(f);
    }
    if (tid < 192) {
        const int k = tid >> 5, c = tid & 31;
        const int col = ct * 32 + c;
        const float f = (col < HREAL) ? W_fc2b[(size_t)k * HREAL + col] : 0.f;
        WS[tid] = f2bf(f);
    }
    for (int i = tid; i < NATOM * NNB; i += 256) PL[i] = pk[b * NATOM * NNB + i];
    for (int i = tid; i < NATOM; i += 256) ML[i] = (u8)(maska[b * NATOM + i] != 0);
    __syncthreads();

    // ---- bnb slice (no bias) ----
    for (int i = tid; i < NBOND * 16; i += 256) {
        const int r = i >> 4, cp = i & 15;
        float lo = 0.f, hi = 0.f;
#pragma unroll
        for (int k = 0; k < BFDIM; ++k) {
            const float bv = bfu(BFL[r * 8 + k]);
            const u32 wv2 = *reinterpret_cast<const u32*>(&WS[k * 32 + 2 * cp]);
            lo += bv * bflo(wv2);
            hi += bv * bfhi(wv2);
        }
        BL[r * 16 + cp] = (u32)f2bf(lo) | ((u32)f2bf(hi) << 16);
    }

    // ---- dual GEMM: SL = af@W_fc2[ct], AL = af@W_fc2a[ct] ----
    {
        const int lane = tid & 63;
        const int wv   = tid >> 6;
        const int r1   = imin(wv * 32 + (lane & 31), NATOM - 1);
        const int koff = (lane >> 5) * 8;
        const __hip_bfloat16* arow = af + (size_t)(b * NATOM + r1) * HP + koff;
        f32x16 acc0, acc1;
#pragma unroll
        for (int r = 0; r < 16; ++r) { acc0[r] = 0.f; acc1[r] = 0.f; }
        const short8* w0 = WL + lane;
        const short8* w1 = WL + 1280 + lane;
#pragma unroll
        for (int ch = 0; ch < 2; ++ch) {
            short8 a[10];
#pragma unroll
            for (int kt = 0; kt < 10; ++kt)
                a[kt] = *reinterpret_cast<const short8*>(arow + (ch * 10 + kt) * 16);
#pragma unroll
            for (int kt = 0; kt < 10; ++kt) {
                acc0 = __builtin_amdgcn_mfma_f32_32x32x16_bf16(a[kt], w0[(ch * 10 + kt) * 64], acc0, 0, 0, 0);
                acc1 = __builtin_amdgcn_mfma_f32_32x32x16_bf16(a[kt], w1[(ch * 10 + kt) * 64], acc1, 0, 0, 0);
            }
        }
        const int col = lane & 31;
#pragma unroll
        for (int r = 0; r < 16; ++r) {
            const int row = wv * 32 + (r & 3) + 8 * (r >> 2) + 4 * (lane >> 5);
            if (row < NATOM) {
                SL[row * 32 + col] = f2bf(acc0[r]);
                AL[row * 32 + col] = f2bf(acc1[r]);
            }
        }
    }
    __syncthreads();

    // ---- product: out = maska ? selfF * sum_j mask (A2f[ag]*bnb[bg]) : 0 ----
    for (int i = tid; i < NATOM * 16; i += 256) {
        const int row = i >> 4, cp = i & 15;
        const int c = ct * 32 + 2 * cp;
        if (c >= HREAL) continue;
        float lo = 0.f, hi = 0.f;
#pragma unroll
        for (int j = 0; j < NNB; ++j) {
            const u32 w = PL[row * NNB + j];
            if ((int)w < 0) {
                const int a  = (w >> 16) & 0xff;
                const int bo = w & 0xffff;
                const u32 va = *reinterpret_cast<const u32*>(&AL[a * 32 + 2 * cp]);
                const u32 vb = BL[bo * 16 + cp];
                lo += bflo(va) * bflo(vb);
                hi += bfhi(va) * bfhi(vb);
            }
        }
        float2 r2;
        r2.x = 0.f; r2.y = 0.f;
        if (ML[row]) {
            const u32 s = *reinterpret_cast<const u32*>(&SL[row * 32 + 2 * cp]);
            r2.x = bflo(s) * lo;
            r2.y = bfhi(s) * hi;
        }
        *reinterpret_cast<float2*>(out + (size_t)(b * NATOM + row) * HREAL + c) = r2;
    }
}

extern "C" void kernel_launch(void* const* d_in, const int* in_sizes, int n_in,
                              void* d_out, int out_size, void* d_ws, size_t ws_size,
                              hipStream_t stream) {
    const float* A1        = (const float*)d_in[0];
    const float* bond      = (const float*)d_in[1];
    const int*   ag        = (const int*)d_in[2];
    const int*   bg        = (const int*)d_in[3];
    const int*   maskn     = (const int*)d_in[6];
    const int*   maska     = (const int*)d_in[7];
    const float* W_fc1     = (const float*)d_in[8];
    const float* W_gc_nei  = (const float*)d_in[9];
    const float* b_gc_nei  = (const float*)d_in[10];
    const float* W_gc_atom = (const float*)d_in[11];
    const float* b_gc_atom = (const float*)d_in[12];
    const float* W_fc2a    = (const float*)d_in[13];
    const float* W_fc2b    = (const float*)d_in[14];
    const float* W_fc2     = (const float*)d_in[15];
    float* out = (float*)d_out;

    // ---- workspace carve-up ----
    char* p = (char*)d_ws;
    auto alloc = [&](size_t bytes) { char* r = p; p += (bytes + 63) & ~(size_t)63; return r; };
    __hip_bfloat16* af0    = (__hip_bfloat16*)alloc((size_t)MA * HP * 2);
    __hip_bfloat16* af1    = (__hip_bfloat16*)alloc((size_t)MA * HP * 2);
    __hip_bfloat16* neib   = (__hip_bfloat16*)alloc((size_t)MA * HP * 2);
    u32*            pk     = (u32*)alloc((size_t)MA * NNB * 4);         // packed nbr table
    short8* pW1  = (short8*)alloc((size_t)NCT32 * 6  * 64 * 16);        // fc1          K=96
    short8* pWnei= (short8*)alloc((size_t)NCT32 * 20 * 64 * 16);        // gc_nei[:H]   K=320
    short8* pWga = (short8*)alloc((size_t)NCT32 * 40 * 64 * 16);        // gc_atom cat  K=640
    short8* pWfd = (short8*)alloc((size_t)2 * NCT32 * 20 * 64 * 16);    // fc2 | fc2a   K=320, 20 ct

    // ---- prep: weight packs + pk (565 blocks) ----
    Prep cfg;
    cfg.mn = maskn; cfg.agp = ag; cfg.bgp = bg; cfg.pk = pk;
    //           W                                  dst                          Kreal  KT KTf off blk0
    cfg.j[0] = { W_fc1,                             pW1,                         AFDIM, 6,  6,  0,   0 };
    cfg.j[1] = { W_gc_nei,                          pWnei,                       HREAL, 20, 20, 0,  15 };
    cfg.j[2] = { W_gc_atom,                         pWga,                        HREAL, 20, 40, 0,  65 };
    cfg.j[3] = { W_gc_atom + (size_t)HREAL * HREAL, pWga,                        HREAL, 20, 40, 20, 115 };
    cfg.j[4] = { W_fc2,                             pWfd,                        HREAL, 20, 20, 0, 165 };
    cfg.j[5] = { W_fc2a,                            pWfd + (size_t)NCT32*20*64,  HREAL, 20, 20, 0, 215 };
    prep_all<<<dim3(PREP_BLKS), dim3(256), 0, stream>>>(cfg);

    // ---- opt-in LDS > 64 KB ----
    static int attr_done = 0;
    if (!attr_done) {
        hipFuncSetAttribute((const void*)k_gemm_bot,    hipFuncAttributeMaxDynamicSharedMemorySize, BOT_LDS);
        hipFuncSetAttribute((const void*)k_final_fused, hipFuncAttributeMaxDynamicSharedMemorySize, FIN_LDS);
        attr_done = 1;
    }

    // ---- fc1 (conv folded in) ----
    k_fc1<<<dim3(MA / 64, 5), dim3(128), 0, stream>>>(A1, pW1, af0);

    const dim3 gNUG(BATCH, NCT32);  // (64,10)
    const dim3 gBOT(MA / 128, 5);   // (60,5) 2-ct, R7-proven
    const dim3 t256(256);
    const float* Wgn_bond = W_gc_nei + (size_t)HREAL * HREAL;

    // ---- graph-conv iterations ----
    const __hip_bfloat16* af = af0;
    __hip_bfloat16* afn = af1;
    for (int it = 0; it < 2; ++it) {
        k_nu_gather<<<gNUG, t256, NUG_LDS, stream>>>(
            af, pWnei, bond, Wgn_bond, b_gc_nei, pk, (u32*)neib);
        k_gemm_bot<<<gBOT, t256, BOT_LDS, stream>>>(af, neib, pWga, b_gc_atom, afn);
        const __hip_bfloat16* t = afn; afn = (__hip_bfloat16*)af; af = t;
    }

    // ---- fused final layer ----
    k_final_fused<<<gNUG, t256, FIN_LDS, stream>>>(
        af, pWfd, bond, W_fc2b, pk, maska, out);
}

// Round 11
// 129.352 us; speedup vs baseline: 1.0949x; 1.0949x over previous
//
#include <hip/hip_runtime.h>
#include <hip/hip_bf16.h>

// Problem constants
#define BATCH 64
#define NATOM 120
#define NNB 10
#define NBOND 250
#define AFDIM 82
#define BFDIM 6
#define HREAL 300
#define HP 320            // padded H (bf16 activation row stride); pad cols hold exact 0
#define NCT32 10          // 10 col-tiles of 32 -> 320
#define MA (BATCH*NATOM)  // 7680
#define MB (BATCH*NBOND)  // 16000

typedef short short8 __attribute__((ext_vector_type(8)));   // 8 bf16 (4 VGPRs)
typedef float f32x16 __attribute__((ext_vector_type(16)));  // 32x32 MFMA accumulator
typedef unsigned int u32;
typedef u32 u32x2 __attribute__((ext_vector_type(2)));
typedef unsigned short u16;
typedef unsigned char u8;

__device__ __forceinline__ float bflo(u32 v) { return __builtin_bit_cast(float, v << 16); }
__device__ __forceinline__ float bfhi(u32 v) { return __builtin_bit_cast(float, v & 0xffff0000u); }
__device__ __forceinline__ float bfu(u16 v) { return __builtin_bit_cast(float, (u32)v << 16); }
__device__ __forceinline__ u16 f2bf(float f) {
    __hip_bfloat16 h = __float2bfloat16(f);
    return __builtin_bit_cast(u16, h);
}
__device__ __forceinline__ int imin(int a, int b) { return a < b ? a : b; }

// ================= prep: weight packs + u16-packed nbr table =================
// pk16[i] = mask<<15 | ag<<8 | bg   (ag<120 fits 7 bits, bg<250 fits 8 bits)
struct PackJob { const float* W; short8* dst; int Kreal, KT, KTfull, ktOff, blk0; };
struct Prep {
    const int *mn, *agp, *bgp; u16* pk16;        // packed nbr table [MA*NNB] u16
    PackJob j[6];
};

#define PACK_BLKS 265     // 15 + 50*5
#define PK_BASE   PACK_BLKS
#define PK_BLKS   300     // MA*NNB/256 = 76800/256
#define PREP_BLKS (PK_BASE + PK_BLKS)   // 565

__global__ __launch_bounds__(256) void prep_all(Prep cfg) {
    const int bid = blockIdx.x;
    const int tid = threadIdx.x;
    if (bid < PK_BASE) {
        int ji = 0;
#pragma unroll
        for (int i = 1; i < 6; ++i) if (bid >= cfg.j[i].blk0) ji = i;
        const PackJob J = cfg.j[ji];
        int id = (bid - J.blk0) * 256 + tid;
        int n = NCT32 * J.KT * 64;
        if (id >= n) return;
        int lane = id & 63;
        int kt = (id >> 6) % J.KT;
        int ct = id / (J.KT * 64);
        int col = ct * 32 + (lane & 31);
        int kbase = kt * 16 + (lane >> 5) * 8;
        short8 v;
#pragma unroll
        for (int jj = 0; jj < 8; ++jj) {
            int k = kbase + jj;
            float f = (k < J.Kreal && col < HREAL) ? J.W[(size_t)k * HREAL + col] : 0.f;
            v[jj] = (short)f2bf(f);
        }
        J.dst[(size_t)(ct * J.KTfull + J.ktOff + kt) * 64 + lane] = v;
    } else {
        int id = (bid - PK_BASE) * 256 + tid;     // exact multiple (76800)
        u16 w = 0;
        if (cfg.mn[id])
            w = (u16)(0x8000u | ((u32)cfg.agp[id] << 8) | (u32)cfg.bgp[id]);
        cfg.pk16[id] = w;
    }
}

// ================= fc1: af0 = relu(A1 @ W_fc1), fp32 A read inline =================
__global__ __launch_bounds__(128)
void k_fc1(const float* __restrict__ A1,          // [MA][82] fp32
           const short8* __restrict__ pW1,
           __hip_bfloat16* __restrict__ af0) {
    __shared__ short8 Wl[2 * 6 * 64];
    const int tid  = threadIdx.x;
    const int lane = tid & 63;
    const int wv   = tid >> 6;
    const int m0   = blockIdx.x * 64 + wv * 32;
    const int ct0  = blockIdx.y * 2;
    const int r1   = m0 + (lane & 31);
    const int koff = (lane >> 5) * 8;

    {
        const short8* wsrc = pW1 + (size_t)ct0 * 6 * 64;
#pragma unroll
        for (int i = 0; i < 6; ++i) Wl[i * 128 + tid] = wsrc[i * 128 + tid];
    }
    __syncthreads();

    const float* src = A1 + (size_t)r1 * AFDIM;
    short8 a[6];
#pragma unroll
    for (int g = 0; g < 6; ++g) {
#pragma unroll
        for (int j = 0; j < 8; ++j) {
            const int k = g * 16 + koff + j;
            const float f = (k < AFDIM) ? src[k] : 0.f;
            a[g][j] = (short)f2bf(f);
        }
    }

    f32x16 acc[2];
#pragma unroll
    for (int r = 0; r < 16; ++r) { acc[0][r] = 0.f; acc[1][r] = 0.f; }
    const short8* w0 = Wl + lane;
    const short8* w1 = Wl + 6 * 64 + lane;
#pragma unroll
    for (int g = 0; g < 6; ++g) {
        acc[0] = __builtin_amdgcn_mfma_f32_32x32x16_bf16(a[g], w0[g * 64], acc[0], 0, 0, 0);
        acc[1] = __builtin_amdgcn_mfma_f32_32x32x16_bf16(a[g], w1[g * 64], acc[1], 0, 0, 0);
    }
#pragma unroll
    for (int c = 0; c < 2; ++c) {
        const int col = (ct0 + c) * 32 + (lane & 31);
#pragma unroll
        for (int r = 0; r < 16; ++r) {
            const int row = m0 + (r & 3) + 8 * (r >> 2) + 4 * (lane >> 5);
            af0[(size_t)row * HP + col] = __float2bfloat16(fmaxf(acc[c][r], 0.f));
        }
    }
}

// ================= bot GEMM (R7-proven): afn = relu([af|nei]@W_ga + b_ga), 2 ct, 80KB panel =================
#define BOT_LDS (2 * 40 * 64 * 16)     // 81920 B -> 2 blocks/CU, 300 blocks = 1 round
__global__ __launch_bounds__(256)
void k_gemm_bot(const __hip_bfloat16* __restrict__ af,
                const __hip_bfloat16* __restrict__ neib,
                const short8* __restrict__ W,
                const float* __restrict__ b_ga,
                __hip_bfloat16* __restrict__ afn) {
    extern __shared__ short8 Wl[];             // [2*40*64]
    const int tid  = threadIdx.x;
    const int lane = tid & 63;
    const int wv   = tid >> 6;
    const int m0   = blockIdx.x * 128 + wv * 32;
    const int ct0  = blockIdx.y * 2;
    const int r1   = m0 + (lane & 31);
    const int koff = (lane >> 5) * 8;

    {
        const short8* wsrc = W + (size_t)ct0 * 40 * 64;
#pragma unroll
        for (int i = 0; i < 20; ++i) Wl[i * 256 + tid] = wsrc[i * 256 + tid];
    }
    __syncthreads();

    f32x16 acc[2];
#pragma unroll
    for (int r = 0; r < 16; ++r) { acc[0][r] = 0.f; acc[1][r] = 0.f; }
    const short8* w0 = Wl + lane;
    const short8* w1 = Wl + 40 * 64 + lane;

#pragma unroll
    for (int ch = 0; ch < 4; ++ch) {
        short8 a[10];
#pragma unroll
        for (int kt = 0; kt < 10; ++kt) {
            const int g = ch * 10 + kt;
            if (g < 20)
                a[kt] = *reinterpret_cast<const short8*>(af + (size_t)r1 * HP + g * 16 + koff);
            else
                a[kt] = *reinterpret_cast<const short8*>(neib + (size_t)r1 * HP + (g - 20) * 16 + koff);
        }
#pragma unroll
        for (int kt = 0; kt < 10; ++kt) {
            const int g = ch * 10 + kt;
            acc[0] = __builtin_amdgcn_mfma_f32_32x32x16_bf16(a[kt], w0[g * 64], acc[0], 0, 0, 0);
            acc[1] = __builtin_amdgcn_mfma_f32_32x32x16_bf16(a[kt], w1[g * 64], acc[1], 0, 0, 0);
        }
    }

#pragma unroll
    for (int c = 0; c < 2; ++c) {
        const int col = (ct0 + c) * 32 + (lane & 31);
        const float bb = (col < HREAL) ? b_ga[col] : 0.f;
#pragma unroll
        for (int r = 0; r < 16; ++r) {
            const int row = m0 + (r & 3) + 8 * (r >> 2) + 4 * (lane >> 5);
            afn[(size_t)row * HP + col] = __float2bfloat16(fmaxf(acc[c][r] + bb, 0.f));
        }
    }
}

// ================= fused nu-GEMM + gather; 50,944 B LDS -> 3 blocks/CU, 640 blocks = 1 round =================
// LDS: WL 20480 @0 | TL 7680 @20480 | BL 16000 @28160 | PLh 2400 @44160 | BFL 4000 @46560 | WS 384 @50560
#define NUG_LDS (20480 + 7680 + 16000 + 2400 + 4000 + 384)   // 50944
__global__ __launch_bounds__(256)
void k_nu_gather(const __hip_bfloat16* __restrict__ af,
                 const short8* __restrict__ pWnei,
                 const float* __restrict__ bond,      // [B][250][6] fp32
                 const float* __restrict__ Wgn_bond,  // W_gc_nei + 300*300, [6][300]
                 const float* __restrict__ b_gn,      // [300]
                 const u16* __restrict__ pk16,
                 u32* __restrict__ nei) {             // [MA][160]
    extern __shared__ char smraw[];
    short8* WL  = (short8*)smraw;                  // [20*64]
    u16*    TL  = (u16*)(smraw + 20480);           // [120][32]
    u32*    BL  = (u32*)(smraw + 28160);           // [250][16] bondgc slice
    u16*    PLh = (u16*)(smraw + 44160);           // [1200]
    u16*    BFL = (u16*)(smraw + 46560);           // [250][8] bond bf16
    u16*    WS  = (u16*)(smraw + 50560);           // [6][32]  W bond-part slice bf16
    const int b   = blockIdx.x;
    const int ct  = blockIdx.y;
    const int tid = threadIdx.x;

    // ---- stage ----
    {
        const short8* wsrc = pWnei + (size_t)ct * 20 * 64;
#pragma unroll
        for (int i = 0; i < 5; ++i) WL[i * 256 + tid] = wsrc[i * 256 + tid];
    }
    for (int i = tid; i < NBOND * 8; i += 256) {
        const int r = i >> 3, k = i & 7;
        const float f = (k < BFDIM) ? bond[(size_t)(b * NBOND + r) * BFDIM + k] : 0.f;
        BFL[i] = f2bf(f);
    }
    if (tid < 192) {
        const int k = tid >> 5, c = tid & 31;
        const int col = ct * 32 + c;
        const float f = (col < HREAL) ? Wgn_bond[(size_t)k * HREAL + col] : 0.f;
        WS[tid] = f2bf(f);
    }
    for (int i = tid; i < 600; i += 256)
        reinterpret_cast<u32*>(PLh)[i] = reinterpret_cast<const u32*>(pk16)[(size_t)b * 600 + i];
    __syncthreads();

    // ---- bondgc slice: BL[r][cp] = bf16pair( sum_k bond[r,k]*W[k,col] + bias ) ----
    for (int i = tid; i < NBOND * 16; i += 256) {
        const int r = i >> 4, cp = i & 15;
        const int col0 = ct * 32 + 2 * cp;
        float lo = 0.f, hi = 0.f;
#pragma unroll
        for (int k = 0; k < BFDIM; ++k) {
            const float bv = bfu(BFL[r * 8 + k]);
            const u32 wv2 = *reinterpret_cast<const u32*>(&WS[k * 32 + 2 * cp]);
            lo += bv * bflo(wv2);
            hi += bv * bfhi(wv2);
        }
        const float v0 = (col0     < HREAL) ? lo + b_gn[col0]     : 0.f;
        const float v1 = (col0 + 1 < HREAL) ? hi + b_gn[col0 + 1] : 0.f;
        BL[r * 16 + cp] = (u32)f2bf(v0) | ((u32)f2bf(v1) << 16);
    }

    // ---- GEMM: TL = af[b] @ W_nei[ct] ----
    {
        const int lane = tid & 63;
        const int wv   = tid >> 6;
        const int r1   = imin(wv * 32 + (lane & 31), NATOM - 1);
        const int koff = (lane >> 5) * 8;
        const __hip_bfloat16* arow = af + (size_t)(b * NATOM + r1) * HP + koff;
        f32x16 acc;
#pragma unroll
        for (int r = 0; r < 16; ++r) acc[r] = 0.f;
        const short8* w0 = WL + lane;
#pragma unroll
        for (int ch = 0; ch < 2; ++ch) {
            short8 a[10];
#pragma unroll
            for (int kt = 0; kt < 10; ++kt)
                a[kt] = *reinterpret_cast<const short8*>(arow + (ch * 10 + kt) * 16);
#pragma unroll
            for (int kt = 0; kt < 10; ++kt)
                acc = __builtin_amdgcn_mfma_f32_32x32x16_bf16(a[kt], w0[(ch * 10 + kt) * 64], acc, 0, 0, 0);
        }
        const int col = lane & 31;
#pragma unroll
        for (int r = 0; r < 16; ++r) {
            const int row = wv * 32 + (r & 3) + 8 * (r >> 2) + 4 * (lane >> 5);
            if (row < NATOM) TL[row * 32 + col] = f2bf(acc[r]);
        }
    }
    __syncthreads();

    // ---- gather: nei = sum_j relu(T[ag] + bondgc[bg]) ----
    for (int i = tid; i < NATOM * 16; i += 256) {
        const int row = i >> 4, cp = i & 15;
        float lo = 0.f, hi = 0.f;
#pragma unroll
        for (int j = 0; j < NNB; ++j) {
            const u16 w = PLh[row * NNB + j];
            if (w & 0x8000) {
                const int a  = (w >> 8) & 0x7f;
                const int bo = w & 0xff;
                const u32 ta = *reinterpret_cast<const u32*>(&TL[a * 32 + 2 * cp]);
                const u32 tb = BL[bo * 16 + cp];
                lo += fmaxf(bflo(ta) + bflo(tb), 0.f);
                hi += fmaxf(bfhi(ta) + bfhi(tb), 0.f);
            }
        }
        nei[(size_t)(b * NATOM + row) * (HP / 2) + ct * 16 + cp] =
            (u32)f2bf(lo) | ((u32)f2bf(hi) << 16);
    }
}

// ================= fused final; single W panel at a time, acc0 in regs, 51,064 B -> 3 blocks/CU =================
// LDS: WL 20480 @0 | AL 7680 @20480 | BL 16000 @28160 | PLh 2400 @44160 | ML 120 @46560 |
//      BFL 4000 @46680 | WS 384 @50680.  GL f32[120][32]=15360 reuses @0 after GEMMs.
#define FIN_LDS (20480 + 7680 + 16000 + 2400 + 120 + 4000 + 384)   // 51064
__global__ __launch_bounds__(256)
void k_final_fused(const __hip_bfloat16* __restrict__ af,
                   const short8* __restrict__ pWfd,    // fc2 ct 0..9 | fc2a ct 10..19
                   const float* __restrict__ bond,     // [B][250][6] fp32
                   const float* __restrict__ W_fc2b,   // [6][300] fp32
                   const u16* __restrict__ pk16,
                   const int* __restrict__ maska,
                   float* __restrict__ out) {          // [MA][300]
    extern __shared__ char smraw[];
    short8* WL  = (short8*)smraw;                      // [20*64]
    u16*    AL  = (u16*)(smraw + 20480);               // A2f [120][32]
    u32*    BL  = (u32*)(smraw + 28160);               // bnb [250][16]
    u16*    PLh = (u16*)(smraw + 44160);               // [1200]
    u8*     ML  = (u8*)(smraw + 46560);                // [120]
    u16*    BFL = (u16*)(smraw + 46680);               // [250][8]
    u16*    WS  = (u16*)(smraw + 50680);               // [6][32]
    float*  GL  = (float*)smraw;                       // [120][32] gathered sums (reuses WL)
    const int b   = blockIdx.x;
    const int ct  = blockIdx.y;
    const int tid = threadIdx.x;
    const int lane = tid & 63;
    const int wv   = tid >> 6;

    // ---- stage A: fc2a panel + bond/W slices + nbr table + mask ----
    {
        const short8* w2a = pWfd + (size_t)(NCT32 + ct) * 20 * 64;
#pragma unroll
        for (int i = 0; i < 5; ++i) WL[i * 256 + tid] = w2a[i * 256 + tid];
    }
    for (int i = tid; i < NBOND * 8; i += 256) {
        const int r = i >> 3, k = i & 7;
        const float f = (k < BFDIM) ? bond[(size_t)(b * NBOND + r) * BFDIM + k] : 0.f;
        BFL[i] = f2bf(f);
    }
    if (tid < 192) {
        const int k = tid >> 5, c = tid & 31;
        const int col = ct * 32 + c;
        const float f = (col < HREAL) ? W_fc2b[(size_t)k * HREAL + col] : 0.f;
        WS[tid] = f2bf(f);
    }
    for (int i = tid; i < 600; i += 256)
        reinterpret_cast<u32*>(PLh)[i] = reinterpret_cast<const u32*>(pk16)[(size_t)b * 600 + i];
    for (int i = tid; i < NATOM; i += 256) ML[i] = (u8)(maska[b * NATOM + i] != 0);
    __syncthreads();

    // ---- bnb slice (no bias) ----
    for (int i = tid; i < NBOND * 16; i += 256) {
        const int r = i >> 4, cp = i & 15;
        float lo = 0.f, hi = 0.f;
#pragma unroll
        for (int k = 0; k < BFDIM; ++k) {
            const float bv = bfu(BFL[r * 8 + k]);
            const u32 wv2 = *reinterpret_cast<const u32*>(&WS[k * 32 + 2 * cp]);
            lo += bv * bflo(wv2);
            hi += bv * bfhi(wv2);
        }
        BL[r * 16 + cp] = (u32)f2bf(lo) | ((u32)f2bf(hi) << 16);
    }

    // ---- GEMM_a: AL = af @ W_fc2a[ct] ----
    const int r1   = imin(wv * 32 + (lane & 31), NATOM - 1);
    const int koff = (lane >> 5) * 8;
    const __hip_bfloat16* arow = af + (size_t)(b * NATOM + r1) * HP + koff;
    {
        f32x16 acc1;
#pragma unroll
        for (int r = 0; r < 16; ++r) acc1[r] = 0.f;
        const short8* w0 = WL + lane;
#pragma unroll
        for (int ch = 0; ch < 2; ++ch) {
            short8 a[10];
#pragma unroll
            for (int kt = 0; kt < 10; ++kt)
                a[kt] = *reinterpret_cast<const short8*>(arow + (ch * 10 + kt) * 16);
#pragma unroll
            for (int kt = 0; kt < 10; ++kt)
                acc1 = __builtin_amdgcn_mfma_f32_32x32x16_bf16(a[kt], w0[(ch * 10 + kt) * 64], acc1, 0, 0, 0);
        }
        const int col = lane & 31;
#pragma unroll
        for (int r = 0; r < 16; ++r) {
            const int row = wv * 32 + (r & 3) + 8 * (r >> 2) + 4 * (lane >> 5);
            if (row < NATOM) AL[row * 32 + col] = f2bf(acc1[r]);
        }
    }
    __syncthreads();   // AL, BL complete; WL reads done

    // ---- re-stage WL = fc2 panel ----
    {
        const short8* w2 = pWfd + (size_t)ct * 20 * 64;
#pragma unroll
        for (int i = 0; i < 5; ++i) WL[i * 256 + tid] = w2[i * 256 + tid];
    }
    __syncthreads();

    // ---- GEMM_s: acc0 = af @ W_fc2[ct] (stays in registers) ----
    f32x16 acc0;
#pragma unroll
    for (int r = 0; r < 16; ++r) acc0[r] = 0.f;
    {
        const short8* w0 = WL + lane;
#pragma unroll
        for (int ch = 0; ch < 2; ++ch) {
            short8 a[10];
#pragma unroll
            for (int kt = 0; kt < 10; ++kt)
                a[kt] = *reinterpret_cast<const short8*>(arow + (ch * 10 + kt) * 16);
#pragma unroll
            for (int kt = 0; kt < 10; ++kt)
                acc0 = __builtin_amdgcn_mfma_f32_32x32x16_bf16(a[kt], w0[(ch * 10 + kt) * 64], acc0, 0, 0, 0);
        }
    }
    __syncthreads();   // all WL reads done before GL overwrite

    // ---- product: GL[row][c] = sum_j mask (A2f[ag]*bnb[bg]) ----
    for (int i = tid; i < NATOM * 16; i += 256) {
        const int row = i >> 4, cp = i & 15;
        float lo = 0.f, hi = 0.f;
#pragma unroll
        for (int j = 0; j < NNB; ++j) {
            const u16 w = PLh[row * NNB + j];
            if (w & 0x8000) {
                const int a  = (w >> 8) & 0x7f;
                const int bo = w & 0xff;
                const u32 va = *reinterpret_cast<const u32*>(&AL[a * 32 + 2 * cp]);
                const u32 vb = BL[bo * 16 + cp];
                lo += bflo(va) * bflo(vb);
                hi += bfhi(va) * bfhi(vb);
            }
        }
        GL[row * 32 + 2 * cp]     = lo;
        GL[row * 32 + 2 * cp + 1] = hi;
    }
    __syncthreads();

    // ---- epilogue: out = maska ? bf16(selfF) * GL : 0, from MFMA lanes (coalesced) ----
    {
        const int col = ct * 32 + (lane & 31);
        if (col < HREAL) {
#pragma unroll
            for (int r = 0; r < 16; ++r) {
                const int row = wv * 32 + (r & 3) + 8 * (r >> 2) + 4 * (lane >> 5);
                if (row < NATOM) {
                    float v = 0.f;
                    if (ML[row]) v = bfu(f2bf(acc0[r])) * GL[row * 32 + (lane & 31)];
                    out[(size_t)(b * NATOM + row) * HREAL + col] = v;
                }
            }
        }
    }
}

extern "C" void kernel_launch(void* const* d_in, const int* in_sizes, int n_in,
                              void* d_out, int out_size, void* d_ws, size_t ws_size,
                              hipStream_t stream) {
    const float* A1        = (const float*)d_in[0];
    const float* bond      = (const float*)d_in[1];
    const int*   ag        = (const int*)d_in[2];
    const int*   bg        = (const int*)d_in[3];
    const int*   maskn     = (const int*)d_in[6];
    const int*   maska     = (const int*)d_in[7];
    const float* W_fc1     = (const float*)d_in[8];
    const float* W_gc_nei  = (const float*)d_in[9];
    const float* b_gc_nei  = (const float*)d_in[10];
    const float* W_gc_atom = (const float*)d_in[11];
    const float* b_gc_atom = (const float*)d_in[12];
    const float* W_fc2a    = (const float*)d_in[13];
    const float* W_fc2b    = (const float*)d_in[14];
    const float* W_fc2     = (const float*)d_in[15];
    float* out = (float*)d_out;

    // ---- workspace carve-up ----
    char* p = (char*)d_ws;
    auto alloc = [&](size_t bytes) { char* r = p; p += (bytes + 63) & ~(size_t)63; return r; };
    __hip_bfloat16* af0    = (__hip_bfloat16*)alloc((size_t)MA * HP * 2);
    __hip_bfloat16* af1    = (__hip_bfloat16*)alloc((size_t)MA * HP * 2);
    __hip_bfloat16* neib   = (__hip_bfloat16*)alloc((size_t)MA * HP * 2);
    u16*            pk16   = (u16*)alloc((size_t)MA * NNB * 2);         // packed nbr table u16
    short8* pW1  = (short8*)alloc((size_t)NCT32 * 6  * 64 * 16);        // fc1          K=96
    short8* pWnei= (short8*)alloc((size_t)NCT32 * 20 * 64 * 16);        // gc_nei[:H]   K=320
    short8* pWga = (short8*)alloc((size_t)NCT32 * 40 * 64 * 16);        // gc_atom cat  K=640
    short8* pWfd = (short8*)alloc((size_t)2 * NCT32 * 20 * 64 * 16);    // fc2 | fc2a   K=320, 20 ct

    // ---- prep: weight packs + pk16 (565 blocks) ----
    Prep cfg;
    cfg.mn = maskn; cfg.agp = ag; cfg.bgp = bg; cfg.pk16 = pk16;
    //           W                                  dst                          Kreal  KT KTf off blk0
    cfg.j[0] = { W_fc1,                             pW1,                         AFDIM, 6,  6,  0,   0 };
    cfg.j[1] = { W_gc_nei,                          pWnei,                       HREAL, 20, 20, 0,  15 };
    cfg.j[2] = { W_gc_atom,                         pWga,                        HREAL, 20, 40, 0,  65 };
    cfg.j[3] = { W_gc_atom + (size_t)HREAL * HREAL, pWga,                        HREAL, 20, 40, 20, 115 };
    cfg.j[4] = { W_fc2,                             pWfd,                        HREAL, 20, 20, 0, 165 };
    cfg.j[5] = { W_fc2a,                            pWfd + (size_t)NCT32*20*64,  HREAL, 20, 20, 0, 215 };
    prep_all<<<dim3(PREP_BLKS), dim3(256), 0, stream>>>(cfg);

    // ---- opt-in LDS > 64 KB (bot only) ----
    static int attr_done = 0;
    if (!attr_done) {
        hipFuncSetAttribute((const void*)k_gemm_bot, hipFuncAttributeMaxDynamicSharedMemorySize, BOT_LDS);
        attr_done = 1;
    }

    // ---- fc1 (conv folded in) ----
    k_fc1<<<dim3(MA / 64, 5), dim3(128), 0, stream>>>(A1, pW1, af0);

    const dim3 gNUG(BATCH, NCT32);  // (64,10) -> 640 blocks @ 3/CU = 1 round
    const dim3 gBOT(MA / 128, 5);   // (60,5) 2-ct @ 2/CU = 1 round
    const dim3 t256(256);
    const float* Wgn_bond = W_gc_nei + (size_t)HREAL * HREAL;

    // ---- graph-conv iterations ----
    const __hip_bfloat16* af = af0;
    __hip_bfloat16* afn = af1;
    for (int it = 0; it < 2; ++it) {
        k_nu_gather<<<gNUG, t256, NUG_LDS, stream>>>(
            af, pWnei, bond, Wgn_bond, b_gc_nei, pk16, (u32*)neib);
        k_gemm_bot<<<gBOT, t256, BOT_LDS, stream>>>(af, neib, pWga, b_gc_atom, afn);
        const __hip_bfloat16* t = afn; afn = (__hip_bfloat16*)af; af = t;
    }

    // ---- fused final layer ----
    k_final_fused<<<gNUG, t256, FIN_LDS, stream>>>(
        af, pWfd, bond, W_fc2b, pk16, maska, out);
}